// Round 1
// 549.943 us; speedup vs baseline: 1.2075x; 1.2075x over previous
//
#include <hip/hip_runtime.h>
#include <hip/hip_bf16.h>
#include <math.h>

#define HIDDEN 2560
#define NH 32
#define NKV 8
#define HD 80
#define BATCH 2
#define SEQ 2048
#define QH_COLS (NH*HD)    // 2560
#define KV_COLS (NKV*HD)   // 640
#define ROWS (BATCH*SEQ)   // 4096

typedef __attribute__((ext_vector_type(4))) float floatx4;
typedef __attribute__((ext_vector_type(16))) float floatx16;
typedef __attribute__((ext_vector_type(8))) short shortx8;
typedef __attribute__((ext_vector_type(4))) unsigned short u16x4;
typedef unsigned short u16;

__device__ inline u16 f2bf(float f) { __hip_bfloat16 h = __float2bfloat16(f); return *(u16*)&h; }
__device__ inline int swz(int r) { return (r + (r >> 2)) & 3; }
__device__ inline void storeC(float v, float* p) { *p = v; }
__device__ inline void storeC(float v, u16* p) { *p = f2bf(v); }

#if __has_builtin(__builtin_amdgcn_exp2f)
__device__ inline float fexp2(float x) { return __builtin_amdgcn_exp2f(x); }
#else
__device__ inline float fexp2(float x) { return __expf(x * 0.6931471805599453f); }
#endif

// packed f32x2 -> bf16x2 (low16 = first arg)
__device__ __forceinline__ unsigned cvtpk(float lo, float hi2) {
    unsigned r;
    asm("v_cvt_pk_bf16_f32 %0, %1, %2" : "=v"(r) : "v"(lo), "v"(hi2));
    return r;
}
// swap a.rows[32:63] <-> b.rows[0:31]
__device__ __forceinline__ void pl32swap(unsigned &a, unsigned &b) {
#if __has_builtin(__builtin_amdgcn_permlane32_swap)
    auto r = __builtin_amdgcn_permlane32_swap(a, b, false, false);
    a = r[0]; b = r[1];
#else
    asm("v_permlane32_swap_b32 %0, %1" : "+v"(a), "+v"(b));
#endif
}

// ---------------- fp32 -> bf16 elementwise (x) ----------------
__global__ __launch_bounds__(256) void conv_bf16(const float* __restrict__ x,
                                                 u16* __restrict__ y) {
    int i = (blockIdx.x * 256 + threadIdx.x) * 4;
    float4 v = *(const float4*)(x + i);
    u16x4 o = { f2bf(v.x), f2bf(v.y), f2bf(v.z), f2bf(v.w) };
    *(u16x4*)(y + i) = o;
}

// ---------------- fp32 [K][N] -> bf16 [N][K] transpose-convert ----------------
__global__ __launch_bounds__(256) void transpose_conv(const float* __restrict__ W,
                                                      u16* __restrict__ Wt,
                                                      int K, int N) {
    __shared__ float tile[64][65];
    const int tid = threadIdx.x;
    const int n0 = blockIdx.x * 64, k0 = blockIdx.y * 64;
    const int r = tid >> 4, c4 = (tid & 15) * 4;
#pragma unroll
    for (int i = 0; i < 4; i++) {
        float4 v = *(const float4*)(W + (size_t)(k0 + r + i * 16) * N + n0 + c4);
        tile[r + i * 16][c4 + 0] = v.x;
        tile[r + i * 16][c4 + 1] = v.y;
        tile[r + i * 16][c4 + 2] = v.z;
        tile[r + i * 16][c4 + 3] = v.w;
    }
    __syncthreads();
    const int n = tid >> 2, kg = (tid & 3) * 16;
    __align__(16) u16 tmp[16];
#pragma unroll
    for (int j = 0; j < 16; j++) tmp[j] = f2bf(tile[kg + j][n]);
    u16* dst = Wt + (size_t)(n0 + n) * K + k0 + kg;
    *(uint4*)dst = *(const uint4*)tmp;
    *(uint4*)(dst + 8) = *(const uint4*)(tmp + 8);
}

// ---------------- bf16 MFMA GEMM: C[M,N] = A[M,K] @ Bt[N,K]^T ----------------
template <typename OutT>
__global__ __launch_bounds__(256) void gemm_mfma(const u16* __restrict__ A,
                                                 const u16* __restrict__ Bt,
                                                 OutT* __restrict__ C,
                                                 int M, int N, int K) {
    __shared__ __align__(16) u16 As[128 * 32];
    __shared__ __align__(16) u16 Bs[128 * 32];
    const int tid = threadIdx.x;
    const int wave = tid >> 6, lane = tid & 63;
    const int m16 = lane & 15, quad = lane >> 4;
    const int wr = wave >> 1, wc = wave & 1;
    const int bm = blockIdx.y * 128, bn = blockIdx.x * 128;

    const u16* gA[2]; const u16* gB[2]; u16* lA[2]; u16* lB[2];
#pragma unroll
    for (int i = 0; i < 2; i++) {
        int c = wave + i * 4;
        int o = c * 1024 + lane * 16;
        int r = o >> 6;
        int s = (o >> 4) & 3;
        int kb = s ^ swz(r);
        gA[i] = A  + (size_t)(bm + r) * K + kb * 8;
        gB[i] = Bt + (size_t)(bn + r) * K + kb * 8;
        lA[i] = As + (o >> 1);
        lB[i] = Bs + (o >> 1);
    }
    int offA[4], offB[4];
#pragma unroll
    for (int i = 0; i < 4; i++) {
        int ra = wr * 64 + i * 16 + m16;
        offA[i] = ra * 32 + (quad ^ swz(ra)) * 8;
        int rb = wc * 64 + i * 16 + m16;
        offB[i] = rb * 32 + (quad ^ swz(rb)) * 8;
    }

    floatx4 acc[4][4];
#pragma unroll
    for (int i = 0; i < 4; i++)
#pragma unroll
        for (int j = 0; j < 4; j++) acc[i][j] = (floatx4){0.f, 0.f, 0.f, 0.f};

    for (int k0 = 0; k0 < K; k0 += 32) {
#pragma unroll
        for (int i = 0; i < 2; i++) {
            __builtin_amdgcn_global_load_lds(
                (const __attribute__((address_space(1))) unsigned int*)(gA[i] + k0),
                (__attribute__((address_space(3))) unsigned int*)lA[i], 16, 0, 0);
            __builtin_amdgcn_global_load_lds(
                (const __attribute__((address_space(1))) unsigned int*)(gB[i] + k0),
                (__attribute__((address_space(3))) unsigned int*)lB[i], 16, 0, 0);
        }
        __syncthreads();
        shortx8 af[4], bfr[4];
#pragma unroll
        for (int i = 0; i < 4; i++) af[i] = *(const shortx8*)(As + offA[i]);
#pragma unroll
        for (int j = 0; j < 4; j++) bfr[j] = *(const shortx8*)(Bs + offB[j]);
#pragma unroll
        for (int i = 0; i < 4; i++)
#pragma unroll
            for (int j = 0; j < 4; j++)
                acc[i][j] = __builtin_amdgcn_mfma_f32_16x16x32_bf16(af[i], bfr[j], acc[i][j], 0, 0, 0);
        __syncthreads();
    }
#pragma unroll
    for (int i = 0; i < 4; i++)
#pragma unroll
        for (int j = 0; j < 4; j++)
#pragma unroll
            for (int p = 0; p < 4; p++) {
                int row = bm + wr * 64 + i * 16 + quad * 4 + p;
                int col = bn + wc * 64 + j * 16 + m16;
                storeC(acc[i][j][p], &C[(size_t)row * N + col]);
            }
}

// ---------------- RoPE, in place on bf16 q/k; Q pre-scaled by scale*log2(e) ----------------
__global__ __launch_bounds__(256) void rope_bf16(__hip_bfloat16* __restrict__ qh,
                                                 __hip_bfloat16* __restrict__ kh,
                                                 const float* __restrict__ cf,
                                                 const float* __restrict__ sf) {
    int idx = blockIdx.x * 256 + threadIdx.x;
    int d  = idx % 40;
    int t  = idx / 40;
    int hh = t % (NH + NKV);
    int g  = t / (NH + NKV);
    int s  = g & (SEQ - 1);
    float c1 = cf[s * HD + d],      s1 = sf[s * HD + d];
    float c2 = cf[s * HD + d + 40], s2 = sf[s * HD + d + 40];
    const float qsc = (hh < NH) ? (float)(0.11180339887498949 * 1.4426950408889634) : 1.0f;
    __hip_bfloat16* p = (hh < NH) ? (qh + (size_t)g * QH_COLS + hh * HD)
                                  : (kh + (size_t)g * KV_COLS + (hh - NH) * HD);
    float x1 = __bfloat162float(p[d]);
    float x2 = __bfloat162float(p[d + 40]);
    p[d]      = __float2bfloat16((x1 * c1 - x2 * s1) * qsc);
    p[d + 40] = __float2bfloat16((x2 * c2 + x1 * s2) * qsc);
}

// ---------------- 32x32 MFMA flash attention, S^T formulation ----------------
// Block = 128 Q rows, 4 waves; wave w owns queries qb..qb+31 (qb = qt*128+w*32).
// S^T tile = K.Q^T (32x32): lane's col = its query -> softmax stats lane-local
// (one __shfl_xor(32) folds the two half-lane row sets). P -> bf16 B-fragments
// built in-register via v_cvt_pk_bf16_f32 + v_permlane32_swap_b32 (no LDS P).
// LDS (32 KB): Kbuf = 2x K_sub[10 dc][64 key][8] (double-buffered, staged via
// global_load_lds direct -> conflict-free b128 reads AND writes);
// V_sub[8 kc][96 d][8 key] with row index d^kc (XOR-swizzle: conflict-free PV
// frag reads, ~2-way scatter writes); d rows 80..95 stay zero (pad for 3rd
// 32-row O^T tile). Q staging aliases Kbuf in the prologue.
__device__ __forceinline__ void stage_K(const u16* kg, u16* dst, int wave, int lane) {
#pragma unroll
    for (int t = 0; t < 2; t++) {
        int s = t * 256 + wave * 64 + lane;
        int db = t * 4 + wave;
        __builtin_amdgcn_global_load_lds(
            (const __attribute__((address_space(1))) unsigned int*)(kg + (size_t)lane * KV_COLS + db * 8),
            (__attribute__((address_space(3))) unsigned int*)(dst + s * 8), 16, 0, 0);
    }
    if (wave < 2) {
        int s = 512 + wave * 64 + lane;
        int db = 8 + wave;
        __builtin_amdgcn_global_load_lds(
            (const __attribute__((address_space(1))) unsigned int*)(kg + (size_t)lane * KV_COLS + db * 8),
            (__attribute__((address_space(3))) unsigned int*)(dst + s * 8), 16, 0, 0);
    }
}

__device__ __forceinline__ void load_V(const u16* vg, shortx8* vr, int wave, int lane) {
#pragma unroll
    for (int t = 0; t < 2; t++) {
        int db = t * 4 + wave;
        vr[t] = *(const shortx8*)(vg + (size_t)lane * KV_COLS + db * 8);
    }
    if (wave < 2) vr[2] = *(const shortx8*)(vg + (size_t)lane * KV_COLS + (8 + wave) * 8);
}

__device__ __forceinline__ void scatter_V(u16* Vs, const shortx8* vr, int wave, int lane) {
    const int kc = lane >> 3, jj = lane & 7;
    u16* base = Vs + kc * 768 + jj;
#pragma unroll
    for (int t = 0; t < 2; t++) {
        int db = t * 4 + wave;
#pragma unroll
        for (int i = 0; i < 8; i++) base[db * 64 + ((i ^ kc) << 3)] = vr[t][i];
    }
    if (wave < 2) {
        int db = 8 + wave;
#pragma unroll
        for (int i = 0; i < 8; i++) base[db * 64 + ((i ^ kc) << 3)] = vr[2][i];
    }
}

__global__ __launch_bounds__(256, 3) void attn_mfma(const u16* __restrict__ qg,
                                                    const u16* __restrict__ kgp,
                                                    const u16* __restrict__ vgp,
                                                    u16* __restrict__ ob) {
    __shared__ __align__(16) u16 SM[16384];    // 32 KB
    u16* Kbuf = SM;            // 2 x 5120 u16; also Q staging [128][80] in prologue
    u16* Vs   = SM + 10240;    // 6144 u16 = [8][96][8]

    const int tid  = threadIdx.x;
    const int wave = tid >> 6;
    const int lane = tid & 63;
    const int l31  = lane & 31;
    const int hi   = lane >> 5;

    const int idx = blockIdx.x;                // 1D grid, LPT: qt=15 blocks first
    const int qt  = 15 - (idx >> 6);
    const int hb  = idx & 63;
    const int h   = hb >> 1;
    const int b   = hb & 1;
    const int kvh = h >> 2;
    const int qb  = qt * 128 + wave * 32;      // wave's first query row

    const u16* qgb = qg + (size_t)(b * SEQ + qt * 128) * QH_COLS + h * HD;
    const u16* kg0 = kgp + (size_t)(b * SEQ) * KV_COLS + kvh * HD;
    const u16* vg0 = vgp + (size_t)(b * SEQ) * KV_COLS + kvh * HD;

    // zero V pad rows (d 80..95 of each kc chunk) -- disjoint from Q staging
    {
        int kc = tid >> 5, o = (tid & 31) * 4;
        *(u16x4*)(Vs + kc * 768 + 640 + o) = (u16x4){0, 0, 0, 0};
    }

    // ---- prologue: stage Q -> SM linear [128][80], read frags to regs ----
#pragma unroll
    for (int t = 0; t < 5; t++) {
        int s = t * 256 + tid;
        int row = s / 10, ch = s % 10;
        __builtin_amdgcn_global_load_lds(
            (const __attribute__((address_space(1))) unsigned int*)(qgb + (size_t)row * QH_COLS + ch * 8),
            (__attribute__((address_space(3))) unsigned int*)(SM + s * 8), 16, 0, 0);
    }
    __syncthreads();
    shortx8 qf[5];
    {
        const u16* qrow = SM + (wave * 32 + l31) * 80 + hi * 8;
#pragma unroll
        for (int c = 0; c < 5; c++) qf[c] = *(const shortx8*)(qrow + c * 16);
    }
    __syncthreads();   // all waves' Q reads done; SM free for K

    // per-lane PV read bases: V_sub[kc8=2c+hi][(n*32+l31)^kc8][.]
    int vbase[4];
#pragma unroll
    for (int c = 0; c < 4; c++) {
        int k8 = c * 2 + hi;
        vbase[c] = k8 * 768 + ((l31 & 24) + ((l31 & 7) ^ k8)) * 8;
    }
    const u16* kfp = Kbuf + hi * 512 + l31 * 8;   // + cur*5120 + c*1024 + kr*256

    // ---- stage K0 (direct->LDS) and V0 (regs, then scatter) ----
    stage_K(kg0, Kbuf, wave, lane);
    shortx8 vr[3];
    load_V(vg0, vr, wave, lane);
    __syncthreads();                 // K0 in LDS (barrier drains vmcnt)
    scatter_V(Vs, vr, wave, lane);
    __syncthreads();                 // V0 visible

    floatx16 Oacc[3];
#pragma unroll
    for (int n = 0; n < 3; n++)
#pragma unroll
        for (int r = 0; r < 16; r++) Oacc[n][r] = 0.0f;
    float mrow = -1.0e30f, lrow = 0.0f;
    int cur = 0;
    const int nkt = 2 * qt + 2;

    for (int kt = 0; kt < nkt; kt++) {
        const bool last = (kt == nkt - 1);
        if (!last) {   // prefetch kt+1: K direct into other buffer, V into regs
            const u16* kg = kg0 + (size_t)(kt + 1) * 64 * KV_COLS;
            const u16* vg = vg0 + (size_t)(kt + 1) * 64 * KV_COLS;
            stage_K(kg, Kbuf + (cur ^ 1) * 5120, wave, lane);
            load_V(vg, vr, wave, lane);
        }

        const bool active = (kt * 64 <= qb + 31);
        if (active) {
            const u16* kp = kfp + cur * 5120;
            const bool kr1   = (kt * 64 + 32 <= qb + 31);
            const bool dmask = (kt * 64 + 63 > qb);
            // S^T = K.Q^T : D[key][query], col = query = l31
            floatx16 S0, S1;
            {
                floatx16 s;
#pragma unroll
                for (int r = 0; r < 16; r++) s[r] = 0.0f;
#pragma unroll
                for (int c = 0; c < 5; c++) {
                    shortx8 kf = *(const shortx8*)(kp + c * 1024);
                    s = __builtin_amdgcn_mfma_f32_32x32x16_bf16(kf, qf[c], s, 0, 0, 0);
                }
                S0 = s;
            }
            if (kr1) {
                floatx16 s;
#pragma unroll
                for (int r = 0; r < 16; r++) s[r] = 0.0f;
#pragma unroll
                for (int c = 0; c < 5; c++) {
                    shortx8 kf = *(const shortx8*)(kp + c * 1024 + 256);
                    s = __builtin_amdgcn_mfma_f32_32x32x16_bf16(kf, qf[c], s, 0, 0, 0);
                }
                S1 = s;
            }
            const int qrel = qb + l31 - kt * 64;
            if (dmask) {
#pragma unroll
                for (int r = 0; r < 16; r++) {
                    int rr = (r & 3) + 8 * (r >> 2) + 4 * hi;
                    if (rr > qrel) S0[r] = -1.0e30f;
                    if (kr1 && (32 + rr) > qrel) S1[r] = -1.0e30f;
                }
            }
            // online softmax (log2 domain), defer-max THR=8
            float mx = mrow;
#pragma unroll
            for (int r = 0; r < 16; r++) mx = fmaxf(mx, S0[r]);
            if (kr1) {
#pragma unroll
                for (int r = 0; r < 16; r++) mx = fmaxf(mx, S1[r]);
            }
            mx = fmaxf(mx, __shfl_xor(mx, 32));
            if (!__all(mx - mrow <= 8.0f)) {
                float alpha = fexp2(mrow - mx);
                lrow *= alpha;
#pragma unroll
                for (int n = 0; n < 3; n++)
#pragma unroll
                    for (int r = 0; r < 16; r++) Oacc[n][r] *= alpha;
                mrow = mx;
            }
            float rsum = 0.0f;
#pragma unroll
            for (int r = 0; r < 16; r++) { float p = fexp2(S0[r] - mrow); rsum += p; S0[r] = p; }
            if (kr1) {
#pragma unroll
                for (int r = 0; r < 16; r++) { float p = fexp2(S1[r] - mrow); rsum += p; S1[r] = p; }
            }
            rsum += __shfl_xor(rsum, 32);
            lrow += rsum;

            // P -> bf16 B-frags in-register; O^T += V^T.P
#pragma unroll
            for (int kr = 0; kr < 2; kr++) {
                if (kr == 1 && !kr1) break;
                floatx16& Sv = (kr == 0) ? S0 : S1;
                unsigned d0[4], d1[4];
#pragma unroll
                for (int m = 0; m < 4; m++) {
                    d0[m] = cvtpk(Sv[4 * m + 0], Sv[4 * m + 1]);
                    d1[m] = cvtpk(Sv[4 * m + 2], Sv[4 * m + 3]);
                }
#pragma unroll
                for (int cb = 0; cb < 2; cb++) {
                    int c = kr * 2 + cb;
                    if (kt * 64 + c * 16 > qb + 31) break;
                    unsigned x0 = d0[2 * cb], y0 = d0[2 * cb + 1];
                    unsigned x1 = d1[2 * cb], y1 = d1[2 * cb + 1];
                    pl32swap(x0, y0);
                    pl32swap(x1, y1);
                    union { unsigned u[4]; shortx8 s8; } pf;
                    pf.u[0] = x0; pf.u[1] = x1; pf.u[2] = y0; pf.u[3] = y1;
#pragma unroll
                    for (int n = 0; n < 3; n++) {
                        shortx8 vf = *(const shortx8*)(Vs + vbase[c] + n * 256);
                        Oacc[n] = __builtin_amdgcn_mfma_f32_32x32x16_bf16(vf, pf.s8, Oacc[n], 0, 0, 0);
                    }
                }
            }
        }

        if (last) break;
        __syncthreads();               // all waves done with Vs & Kbuf[cur]; K(kt+1) drained
        scatter_V(Vs, vr, wave, lane); // write V(kt+1)
        cur ^= 1;
        __syncthreads();               // Vs ready
    }

    // epilogue: O[q][d] from O^T tiles; d = n*32 + 8m + 4hi + p
    const float invl = 1.0f / lrow;
    u16* op = ob + (size_t)(b * SEQ + qt * 128 + wave * 32 + l31) * QH_COLS + h * HD + 4 * hi;
#pragma unroll
    for (int n = 0; n < 3; n++) {
        const int mmax = (n == 2) ? 2 : 4;
#pragma unroll
        for (int m = 0; m < mmax; m++) {
            u16x4 o4 = { f2bf(Oacc[n][4 * m + 0] * invl), f2bf(Oacc[n][4 * m + 1] * invl),
                         f2bf(Oacc[n][4 * m + 2] * invl), f2bf(Oacc[n][4 * m + 3] * invl) };
            *(u16x4*)(op + n * 32 + 8 * m) = o4;
        }
    }
}

// ---------------- launch ----------------
extern "C" void kernel_launch(void* const* d_in, const int* in_sizes, int n_in,
                              void* d_out, int out_size, void* d_ws, size_t ws_size,
                              hipStream_t stream) {
    const float* x    = (const float*)d_in[0];
    const float* cf   = (const float*)d_in[1];
    const float* sf   = (const float*)d_in[2];
    const float* Wq   = (const float*)d_in[3];
    const float* Wk   = (const float*)d_in[4];
    const float* Wv   = (const float*)d_in[5];
    const float* Wo   = (const float*)d_in[6];
    float* out = (float*)d_out;

    u16* xh  = (u16*)d_ws;                             // 4096x2560; later reused as obh
    u16* Wqt = xh  + (size_t)ROWS * QH_COLS;           // 2560x2560 (Nt x K)
    u16* Wkt = Wqt + (size_t)QH_COLS * HIDDEN;         // 640x2560
    u16* Wvt = Wkt + (size_t)KV_COLS * HIDDEN;         // 640x2560
    u16* Wot = Wvt + (size_t)KV_COLS * HIDDEN;         // 2560x2560
    u16* qh  = Wot + (size_t)HIDDEN * QH_COLS;         // 4096x2560
    u16* kh  = qh  + (size_t)ROWS * QH_COLS;           // 4096x640
    u16* vh  = kh  + (size_t)ROWS * KV_COLS;           // 4096x640
    u16* obh = xh;                                     // alias: x dead after projections

    dim3 blk(256);
    conv_bf16<<<(ROWS * HIDDEN / 4) / 256, blk, 0, stream>>>(x, xh);
    transpose_conv<<<dim3(QH_COLS / 64, HIDDEN / 64), blk, 0, stream>>>(Wq, Wqt, HIDDEN, QH_COLS);
    transpose_conv<<<dim3(KV_COLS / 64, HIDDEN / 64), blk, 0, stream>>>(Wk, Wkt, HIDDEN, KV_COLS);
    transpose_conv<<<dim3(KV_COLS / 64, HIDDEN / 64), blk, 0, stream>>>(Wv, Wvt, HIDDEN, KV_COLS);
    transpose_conv<<<dim3(HIDDEN / 64, QH_COLS / 64), blk, 0, stream>>>(Wo, Wot, QH_COLS, HIDDEN);

    gemm_mfma<u16><<<dim3(QH_COLS / 128, ROWS / 128), blk, 0, stream>>>(xh, Wqt, qh, ROWS, QH_COLS, HIDDEN);
    gemm_mfma<u16><<<dim3(KV_COLS / 128, ROWS / 128), blk, 0, stream>>>(xh, Wkt, kh, ROWS, KV_COLS, HIDDEN);
    gemm_mfma<u16><<<dim3(KV_COLS / 128, ROWS / 128), blk, 0, stream>>>(xh, Wvt, vh, ROWS, KV_COLS, HIDDEN);

    rope_bf16<<<(ROWS * (NH + NKV) * 40) / 256, blk, 0, stream>>>((__hip_bfloat16*)qh, (__hip_bfloat16*)kh, cf, sf);
    attn_mfma<<<dim3(16 * 64), blk, 0, stream>>>(qh, kh, vh, obh);

    gemm_mfma<float><<<dim3(HIDDEN / 128, ROWS / 128), blk, 0, stream>>>(obh, Wot, out, ROWS, HIDDEN, QH_COLS);
}

// Round 2
// 479.949 us; speedup vs baseline: 1.3836x; 1.1458x over previous
//
#include <hip/hip_runtime.h>
#include <hip/hip_bf16.h>
#include <math.h>

#define HIDDEN 2560
#define NH 32
#define NKV 8
#define HD 80
#define BATCH 2
#define SEQ 2048
#define QH_COLS (NH*HD)                  // 2560
#define KV_COLS (NKV*HD)                 // 640
#define QKV_COLS (QH_COLS + 2*KV_COLS)   // 3840 fused q|k|v row
#define ROWS (BATCH*SEQ)                 // 4096

typedef __attribute__((ext_vector_type(4))) float floatx4;
typedef __attribute__((ext_vector_type(16))) float floatx16;
typedef __attribute__((ext_vector_type(8))) short shortx8;
typedef __attribute__((ext_vector_type(4))) unsigned short u16x4;
typedef unsigned short u16;

__device__ inline u16 f2bf(float f) { __hip_bfloat16 h = __float2bfloat16(f); return *(u16*)&h; }
__device__ inline void storeC(float v, float* p) { *p = v; }
__device__ inline void storeC(float v, u16* p) { *p = f2bf(v); }

#if __has_builtin(__builtin_amdgcn_exp2f)
__device__ inline float fexp2(float x) { return __builtin_amdgcn_exp2f(x); }
#else
__device__ inline float fexp2(float x) { return __expf(x * 0.6931471805599453f); }
#endif

// packed f32x2 -> bf16x2 (low16 = first arg)
__device__ __forceinline__ unsigned cvtpk(float lo, float hi2) {
    unsigned r;
    asm("v_cvt_pk_bf16_f32 %0, %1, %2" : "=v"(r) : "v"(lo), "v"(hi2));
    return r;
}
// swap a.rows[32:63] <-> b.rows[0:31]
__device__ __forceinline__ void pl32swap(unsigned &a, unsigned &b) {
#if __has_builtin(__builtin_amdgcn_permlane32_swap)
    auto r = __builtin_amdgcn_permlane32_swap(a, b, false, false);
    a = r[0]; b = r[1];
#else
    asm("v_permlane32_swap_b32 %0, %1" : "+v"(a), "+v"(b));
#endif
}

#define GLL(gp, lp) __builtin_amdgcn_global_load_lds( \
    (const __attribute__((address_space(1))) unsigned int*)(gp), \
    (__attribute__((address_space(3))) unsigned int*)(lp), 16, 0, 0)

// ---------------- fp32 -> bf16 elementwise (x) ----------------
__global__ __launch_bounds__(256) void conv_bf16(const float* __restrict__ x,
                                                 u16* __restrict__ y) {
    int i = (blockIdx.x * 256 + threadIdx.x) * 4;
    float4 v = *(const float4*)(x + i);
    u16x4 o = { f2bf(v.x), f2bf(v.y), f2bf(v.z), f2bf(v.w) };
    *(u16x4*)(y + i) = o;
}

// ---------------- fp32 [K][N] -> bf16 [N][K] transpose-convert ----------------
__global__ __launch_bounds__(256) void transpose_conv(const float* __restrict__ W,
                                                      u16* __restrict__ Wt,
                                                      int K, int N) {
    __shared__ float tile[64][65];
    const int tid = threadIdx.x;
    const int n0 = blockIdx.x * 64, k0 = blockIdx.y * 64;
    const int r = tid >> 4, c4 = (tid & 15) * 4;
#pragma unroll
    for (int i = 0; i < 4; i++) {
        float4 v = *(const float4*)(W + (size_t)(k0 + r + i * 16) * N + n0 + c4);
        tile[r + i * 16][c4 + 0] = v.x;
        tile[r + i * 16][c4 + 1] = v.y;
        tile[r + i * 16][c4 + 2] = v.z;
        tile[r + i * 16][c4 + 3] = v.w;
    }
    __syncthreads();
    const int n = tid >> 2, kg = (tid & 3) * 16;
    __align__(16) u16 tmp[16];
#pragma unroll
    for (int j = 0; j < 16; j++) tmp[j] = f2bf(tile[kg + j][n]);
    u16* dst = Wt + (size_t)(n0 + n) * K + k0 + kg;
    *(uint4*)dst = *(const uint4*)tmp;
    *(uint4*)(dst + 8) = *(const uint4*)(tmp + 8);
}

// ---------------- 256x256 8-phase counted-vmcnt bf16 GEMM ----------------
// C[M,N] = A[M,K] @ Bt[N,K]^T.  512 threads = 8 waves (2M x 4N), per-wave out
// 128x64 (acc[8][4] 16x16 frags).  BK=64; LDS = 2 K-tile buffers x (A,B) x
// chunked [kc][256 rows][8] = 128 KB.  Chunked layout: frag ds_read_b128 and
// global_load_lds staging writes are both bank-conflict-free.
// Schedule per K-tile (4 phases): each phase reg-loads ONE 16KB region
// (ph1 A-klo + B01-klo, ph2 B23-klo, ph3 A-khi + B01-khi, ph4 B23-khi) and
// immediately restages that SAME region with K-tile kt+2's data -> an early-
// landing load can only clobber data already consumed into registers.
// vmcnt(8) once per K-tile BEFORE the end barrier (tile kt+1's 8 loads
// retired, tile kt+2's 8 in flight); never vmcnt(0) in the loop; raw
// s_barrier only (no __syncthreads = no forced vmcnt(0) drain); setprio(1)
// around each 16-MFMA cluster (T5).
template <typename OutT>
__global__ __launch_bounds__(512, 2) void gemm256(const u16* __restrict__ A,
                                                  const u16* __restrict__ Bt,
                                                  OutT* __restrict__ C,
                                                  int M, int N, int K) {
    __shared__ __align__(16) u16 SM[65536];   // [buf][A|B][khalf][kc:2][256][8]
    const int tid = threadIdx.x;
    const int wave = tid >> 6, lane = tid & 63;
    const int m16 = lane & 15, quad = lane >> 4;
    const int wm = wave >> 2, wn = wave & 3;
    const int bm = blockIdx.y * 256, bn = blockIdx.x * 256;

    // staging: region = 4 kc x 256 rows x 8 u16 (16KB); per wave 2 GLLs,
    // inst q covers kc = (wave>>2) + 2q, rows (wave&3)*64 + lane.
    const int srow = (wave & 3) * 64 + lane;
    const int skc  = wave >> 2;
    const u16* pA = A  + (size_t)(bm + srow) * K + skc * 8;
    const u16* pB = Bt + (size_t)(bn + srow) * K + skc * 8;
    u16* lsA = SM + skc * 2048 + (wave & 3) * 512 + lane * 8;
    u16* lsB = lsA + 32768;

    // fragment read offsets: + buf*16384 + khalf*8192 + frag*128
    const int aoff = quad * 2048 + (wm * 128 + m16) * 8;
    const int boff = quad * 2048 + (wn * 64 + m16) * 8 + 32768;

    floatx4 acc[8][4];
#pragma unroll
    for (int i = 0; i < 8; i++)
#pragma unroll
        for (int j = 0; j < 4; j++) acc[i][j] = (floatx4){0.f, 0.f, 0.f, 0.f};

    const int nkt = K >> 6;   // 40 for K=2560

    // ---- prologue: stage K-tiles 0 and 1 (per tile: Aklo,Bklo,Akhi,Bkhi) ----
#pragma unroll
    for (int t = 0; t < 2; t++) {
        const int tb = t * 16384, tc = t * 64;
        GLL(pA + tc,      lsA + tb);        GLL(pA + tc + 16, lsA + tb + 4096);
        GLL(pB + tc,      lsB + tb);        GLL(pB + tc + 16, lsB + tb + 4096);
        GLL(pA + tc + 32, lsA + tb + 8192); GLL(pA + tc + 48, lsA + tb + 12288);
        GLL(pB + tc + 32, lsB + tb + 8192); GLL(pB + tc + 48, lsB + tb + 12288);
    }
    asm volatile("s_waitcnt vmcnt(8)" ::: "memory");   // tile 0 landed
    __builtin_amdgcn_s_barrier();

    for (int kt = 0; kt < nkt; ++kt) {
        const int ab = (kt & 1) * 16384;        // tile kt+2 -> same buffer
        const bool pf = (kt + 2 < nkt);
        const int pc = (kt + 2) * 64;
        shortx8 af[8], b0, b1, b2, b3;

        // ---- phase 1: A-klo (8) + B{0,1}-klo (2); restage A-klo ----
#pragma unroll
        for (int i = 0; i < 8; i++) af[i] = *(const shortx8*)(SM + ab + aoff + i * 128);
        b0 = *(const shortx8*)(SM + ab + boff);
        b1 = *(const shortx8*)(SM + ab + boff + 128);
        if (pf) { GLL(pA + pc, lsA + ab); GLL(pA + pc + 16, lsA + ab + 4096); }
        __builtin_amdgcn_s_barrier();
        __builtin_amdgcn_s_setprio(1);
#pragma unroll
        for (int i = 0; i < 8; i++) {
            acc[i][0] = __builtin_amdgcn_mfma_f32_16x16x32_bf16(af[i], b0, acc[i][0], 0, 0, 0);
            acc[i][1] = __builtin_amdgcn_mfma_f32_16x16x32_bf16(af[i], b1, acc[i][1], 0, 0, 0);
        }
        __builtin_amdgcn_s_setprio(0);
        __builtin_amdgcn_s_barrier();

        // ---- phase 2: B{2,3}-klo (2); restage B-klo ----
        b2 = *(const shortx8*)(SM + ab + boff + 256);
        b3 = *(const shortx8*)(SM + ab + boff + 384);
        if (pf) { GLL(pB + pc, lsB + ab); GLL(pB + pc + 16, lsB + ab + 4096); }
        __builtin_amdgcn_s_barrier();
        __builtin_amdgcn_s_setprio(1);
#pragma unroll
        for (int i = 0; i < 8; i++) {
            acc[i][2] = __builtin_amdgcn_mfma_f32_16x16x32_bf16(af[i], b2, acc[i][2], 0, 0, 0);
            acc[i][3] = __builtin_amdgcn_mfma_f32_16x16x32_bf16(af[i], b3, acc[i][3], 0, 0, 0);
        }
        __builtin_amdgcn_s_setprio(0);
        __builtin_amdgcn_s_barrier();

        // ---- phase 3: A-khi (8) + B{0,1}-khi (2); restage A-khi ----
#pragma unroll
        for (int i = 0; i < 8; i++) af[i] = *(const shortx8*)(SM + ab + 8192 + aoff + i * 128);
        b0 = *(const shortx8*)(SM + ab + 8192 + boff);
        b1 = *(const shortx8*)(SM + ab + 8192 + boff + 128);
        if (pf) { GLL(pA + pc + 32, lsA + ab + 8192); GLL(pA + pc + 48, lsA + ab + 12288); }
        __builtin_amdgcn_s_barrier();
        __builtin_amdgcn_s_setprio(1);
#pragma unroll
        for (int i = 0; i < 8; i++) {
            acc[i][0] = __builtin_amdgcn_mfma_f32_16x16x32_bf16(af[i], b0, acc[i][0], 0, 0, 0);
            acc[i][1] = __builtin_amdgcn_mfma_f32_16x16x32_bf16(af[i], b1, acc[i][1], 0, 0, 0);
        }
        __builtin_amdgcn_s_setprio(0);
        __builtin_amdgcn_s_barrier();

        // ---- phase 4: B{2,3}-khi (2); restage B-khi; per-tile vmcnt ----
        b2 = *(const shortx8*)(SM + ab + 8192 + boff + 256);
        b3 = *(const shortx8*)(SM + ab + 8192 + boff + 384);
        if (pf) { GLL(pB + pc + 32, lsB + ab + 8192); GLL(pB + pc + 48, lsB + ab + 12288); }
        __builtin_amdgcn_s_barrier();
        __builtin_amdgcn_s_setprio(1);
#pragma unroll
        for (int i = 0; i < 8; i++) {
            acc[i][2] = __builtin_amdgcn_mfma_f32_16x16x32_bf16(af[i], b2, acc[i][2], 0, 0, 0);
            acc[i][3] = __builtin_amdgcn_mfma_f32_16x16x32_bf16(af[i], b3, acc[i][3], 0, 0, 0);
        }
        __builtin_amdgcn_s_setprio(0);
        if (pf) asm volatile("s_waitcnt vmcnt(8)" ::: "memory");   // tile kt+1 landed
        else    asm volatile("s_waitcnt vmcnt(0)" ::: "memory");
        __builtin_amdgcn_s_barrier();
    }

#pragma unroll
    for (int i = 0; i < 8; i++)
#pragma unroll
        for (int j = 0; j < 4; j++)
#pragma unroll
            for (int p = 0; p < 4; p++) {
                int row = bm + wm * 128 + i * 16 + quad * 4 + p;
                int col = bn + wn * 64 + j * 16 + m16;
                storeC(acc[i][j][p], &C[(size_t)row * N + col]);
            }
}

// ---------------- RoPE, in place on fused qkv rows; Q pre-scaled ----------------
__global__ __launch_bounds__(256) void rope_bf16(__hip_bfloat16* __restrict__ qkv,
                                                 const float* __restrict__ cf,
                                                 const float* __restrict__ sf) {
    int idx = blockIdx.x * 256 + threadIdx.x;
    int d  = idx % 40;
    int t  = idx / 40;
    int hh = t % (NH + NKV);
    int g  = t / (NH + NKV);
    int s  = g & (SEQ - 1);
    float c1 = cf[s * HD + d],      s1 = sf[s * HD + d];
    float c2 = cf[s * HD + d + 40], s2 = sf[s * HD + d + 40];
    const float qsc = (hh < NH) ? (float)(0.11180339887498949 * 1.4426950408889634) : 1.0f;
    __hip_bfloat16* p = (hh < NH) ? (qkv + (size_t)g * QKV_COLS + hh * HD)
                                  : (qkv + (size_t)g * QKV_COLS + QH_COLS + (hh - NH) * HD);
    float x1 = __bfloat162float(p[d]);
    float x2 = __bfloat162float(p[d + 40]);
    p[d]      = __float2bfloat16((x1 * c1 - x2 * s1) * qsc);
    p[d + 40] = __float2bfloat16((x2 * c2 + x1 * s2) * qsc);
}

// ---------------- 32x32 MFMA flash attention, S^T formulation ----------------
// (unchanged from round 0 except q/k/v now live in the fused qkv buffer with
// row stride QKV_COLS; q at col 0, k at col 2560, v at col 3200.)
__device__ __forceinline__ void stage_K(const u16* kg, u16* dst, int wave, int lane) {
#pragma unroll
    for (int t = 0; t < 2; t++) {
        int s = t * 256 + wave * 64 + lane;
        int db = t * 4 + wave;
        GLL(kg + (size_t)lane * QKV_COLS + db * 8, dst + s * 8);
    }
    if (wave < 2) {
        int s = 512 + wave * 64 + lane;
        int db = 8 + wave;
        GLL(kg + (size_t)lane * QKV_COLS + db * 8, dst + s * 8);
    }
}

__device__ __forceinline__ void load_V(const u16* vg, shortx8* vr, int wave, int lane) {
#pragma unroll
    for (int t = 0; t < 2; t++) {
        int db = t * 4 + wave;
        vr[t] = *(const shortx8*)(vg + (size_t)lane * QKV_COLS + db * 8);
    }
    if (wave < 2) vr[2] = *(const shortx8*)(vg + (size_t)lane * QKV_COLS + (8 + wave) * 8);
}

__device__ __forceinline__ void scatter_V(u16* Vs, const shortx8* vr, int wave, int lane) {
    const int kc = lane >> 3, jj = lane & 7;
    u16* base = Vs + kc * 768 + jj;
#pragma unroll
    for (int t = 0; t < 2; t++) {
        int db = t * 4 + wave;
#pragma unroll
        for (int i = 0; i < 8; i++) base[db * 64 + ((i ^ kc) << 3)] = vr[t][i];
    }
    if (wave < 2) {
        int db = 8 + wave;
#pragma unroll
        for (int i = 0; i < 8; i++) base[db * 64 + ((i ^ kc) << 3)] = vr[2][i];
    }
}

__global__ __launch_bounds__(256, 3) void attn_mfma(const u16* __restrict__ qkv,
                                                    u16* __restrict__ ob) {
    __shared__ __align__(16) u16 SM[16384];    // 32 KB
    u16* Kbuf = SM;            // 2 x 5120 u16; also Q staging [128][80] in prologue
    u16* Vs   = SM + 10240;    // 6144 u16 = [8][96][8]

    const int tid  = threadIdx.x;
    const int wave = tid >> 6;
    const int lane = tid & 63;
    const int l31  = lane & 31;
    const int hi   = lane >> 5;

    const int idx = blockIdx.x;                // 1D grid, LPT: qt=15 blocks first
    const int qt  = 15 - (idx >> 6);
    const int hb  = idx & 63;
    const int h   = hb >> 1;
    const int b   = hb & 1;
    const int kvh = h >> 2;
    const int qb  = qt * 128 + wave * 32;      // wave's first query row

    const u16* qgb = qkv + (size_t)(b * SEQ + qt * 128) * QKV_COLS + h * HD;
    const u16* kg0 = qkv + (size_t)(b * SEQ) * QKV_COLS + QH_COLS + kvh * HD;
    const u16* vg0 = qkv + (size_t)(b * SEQ) * QKV_COLS + QH_COLS + KV_COLS + kvh * HD;

    // zero V pad rows (d 80..95 of each kc chunk) -- disjoint from Q staging
    {
        int kc = tid >> 5, o = (tid & 31) * 4;
        *(u16x4*)(Vs + kc * 768 + 640 + o) = (u16x4){0, 0, 0, 0};
    }

    // ---- prologue: stage Q -> SM linear [128][80], read frags to regs ----
#pragma unroll
    for (int t = 0; t < 5; t++) {
        int s = t * 256 + tid;
        int row = s / 10, ch = s % 10;
        GLL(qgb + (size_t)row * QKV_COLS + ch * 8, SM + s * 8);
    }
    __syncthreads();
    shortx8 qf[5];
    {
        const u16* qrow = SM + (wave * 32 + l31) * 80 + hi * 8;
#pragma unroll
        for (int c = 0; c < 5; c++) qf[c] = *(const shortx8*)(qrow + c * 16);
    }
    __syncthreads();   // all waves' Q reads done; SM free for K

    // per-lane PV read bases: V_sub[kc8=2c+hi][(n*32+l31)^kc8][.]
    int vbase[4];
#pragma unroll
    for (int c = 0; c < 4; c++) {
        int k8 = c * 2 + hi;
        vbase[c] = k8 * 768 + ((l31 & 24) + ((l31 & 7) ^ k8)) * 8;
    }
    const u16* kfp = Kbuf + hi * 512 + l31 * 8;   // + cur*5120 + c*1024 + kr*256

    // ---- stage K0 (direct->LDS) and V0 (regs, then scatter) ----
    stage_K(kg0, Kbuf, wave, lane);
    shortx8 vr[3];
    load_V(vg0, vr, wave, lane);
    __syncthreads();                 // K0 in LDS (barrier drains vmcnt)
    scatter_V(Vs, vr, wave, lane);
    __syncthreads();                 // V0 visible

    floatx16 Oacc[3];
#pragma unroll
    for (int n = 0; n < 3; n++)
#pragma unroll
        for (int r = 0; r < 16; r++) Oacc[n][r] = 0.0f;
    float mrow = -1.0e30f, lrow = 0.0f;
    int cur = 0;
    const int nkt = 2 * qt + 2;

    for (int kt = 0; kt < nkt; kt++) {
        const bool last = (kt == nkt - 1);
        if (!last) {   // prefetch kt+1: K direct into other buffer, V into regs
            const u16* kg = kg0 + (size_t)(kt + 1) * 64 * QKV_COLS;
            const u16* vg = vg0 + (size_t)(kt + 1) * 64 * QKV_COLS;
            stage_K(kg, Kbuf + (cur ^ 1) * 5120, wave, lane);
            load_V(vg, vr, wave, lane);
        }

        const bool active = (kt * 64 <= qb + 31);
        if (active) {
            const u16* kp = kfp + cur * 5120;
            const bool kr1   = (kt * 64 + 32 <= qb + 31);
            const bool dmask = (kt * 64 + 63 > qb);
            // S^T = K.Q^T : D[key][query], col = query = l31
            floatx16 S0, S1;
            {
                floatx16 s;
#pragma unroll
                for (int r = 0; r < 16; r++) s[r] = 0.0f;
#pragma unroll
                for (int c = 0; c < 5; c++) {
                    shortx8 kf = *(const shortx8*)(kp + c * 1024);
                    s = __builtin_amdgcn_mfma_f32_32x32x16_bf16(kf, qf[c], s, 0, 0, 0);
                }
                S0 = s;
            }
            if (kr1) {
                floatx16 s;
#pragma unroll
                for (int r = 0; r < 16; r++) s[r] = 0.0f;
#pragma unroll
                for (int c = 0; c < 5; c++) {
                    shortx8 kf = *(const shortx8*)(kp + c * 1024 + 256);
                    s = __builtin_amdgcn_mfma_f32_32x32x16_bf16(kf, qf[c], s, 0, 0, 0);
                }
                S1 = s;
            }
            const int qrel = qb + l31 - kt * 64;
            if (dmask) {
#pragma unroll
                for (int r = 0; r < 16; r++) {
                    int rr = (r & 3) + 8 * (r >> 2) + 4 * hi;
                    if (rr > qrel) S0[r] = -1.0e30f;
                    if (kr1 && (32 + rr) > qrel) S1[r] = -1.0e30f;
                }
            }
            // online softmax (log2 domain), defer-max THR=8
            float mx = mrow;
#pragma unroll
            for (int r = 0; r < 16; r++) mx = fmaxf(mx, S0[r]);
            if (kr1) {
#pragma unroll
                for (int r = 0; r < 16; r++) mx = fmaxf(mx, S1[r]);
            }
            mx = fmaxf(mx, __shfl_xor(mx, 32));
            if (!__all(mx - mrow <= 8.0f)) {
                float alpha = fexp2(mrow - mx);
                lrow *= alpha;
#pragma unroll
                for (int n = 0; n < 3; n++)
#pragma unroll
                    for (int r = 0; r < 16; r++) Oacc[n][r] *= alpha;
                mrow = mx;
            }
            float rsum = 0.0f;
#pragma unroll
            for (int r = 0; r < 16; r++) { float p = fexp2(S0[r] - mrow); rsum += p; S0[r] = p; }
            if (kr1) {
#pragma unroll
                for (int r = 0; r < 16; r++) { float p = fexp2(S1[r] - mrow); rsum += p; S1[r] = p; }
            }
            rsum += __shfl_xor(rsum, 32);
            lrow += rsum;

            // P -> bf16 B-frags in-register; O^T += V^T.P
#pragma unroll
            for (int kr = 0; kr < 2; kr++) {
                if (kr == 1 && !kr1) break;
                floatx16& Sv = (kr == 0) ? S0 : S1;
                unsigned d0[4], d1[4];
#pragma unroll
                for (int m = 0; m < 4; m++) {
                    d0[m] = cvtpk(Sv[4 * m + 0], Sv[4 * m + 1]);
                    d1[m] = cvtpk(Sv[4 * m + 2], Sv[4 * m + 3]);
                }
#pragma unroll
                for (int cb = 0; cb < 2; cb++) {
                    int c = kr * 2 + cb;
                    if (kt * 64 + c * 16 > qb + 31) break;
                    unsigned x0 = d0[2 * cb], y0 = d0[2 * cb + 1];
                    unsigned x1 = d1[2 * cb], y1 = d1[2 * cb + 1];
                    pl32swap(x0, y0);
                    pl32swap(x1, y1);
                    union { unsigned u[4]; shortx8 s8; } pf;
                    pf.u[0] = x0; pf.u[1] = x1; pf.u[2] = y0; pf.u[3] = y1;
#pragma unroll
                    for (int n = 0; n < 3; n++) {
                        shortx8 vf = *(const shortx8*)(Vs + vbase[c] + n * 256);
                        Oacc[n] = __builtin_amdgcn_mfma_f32_32x32x16_bf16(vf, pf.s8, Oacc[n], 0, 0, 0);
                    }
                }
            }
        }

        if (last) break;
        __syncthreads();               // all waves done with Vs & Kbuf[cur]; K(kt+1) drained
        scatter_V(Vs, vr, wave, lane); // write V(kt+1)
        cur ^= 1;
        __syncthreads();               // Vs ready
    }

    // epilogue: O[q][d] from O^T tiles; d = n*32 + 8m + 4hi + p
    const float invl = 1.0f / lrow;
    u16* op = ob + (size_t)(b * SEQ + qt * 128 + wave * 32 + l31) * QH_COLS + h * HD + 4 * hi;
#pragma unroll
    for (int n = 0; n < 3; n++) {
        const int mmax = (n == 2) ? 2 : 4;
#pragma unroll
        for (int m = 0; m < mmax; m++) {
            u16x4 o4 = { f2bf(Oacc[n][4 * m + 0] * invl), f2bf(Oacc[n][4 * m + 1] * invl),
                         f2bf(Oacc[n][4 * m + 2] * invl), f2bf(Oacc[n][4 * m + 3] * invl) };
            *(u16x4*)(op + n * 32 + 8 * m) = o4;
        }
    }
}

// ---------------- launch ----------------
extern "C" void kernel_launch(void* const* d_in, const int* in_sizes, int n_in,
                              void* d_out, int out_size, void* d_ws, size_t ws_size,
                              hipStream_t stream) {
    const float* x    = (const float*)d_in[0];
    const float* cf   = (const float*)d_in[1];
    const float* sf   = (const float*)d_in[2];
    const float* Wq   = (const float*)d_in[3];
    const float* Wk   = (const float*)d_in[4];
    const float* Wv   = (const float*)d_in[5];
    const float* Wo   = (const float*)d_in[6];
    float* out = (float*)d_out;

    u16* xh    = (u16*)d_ws;                            // 4096x2560; later reused as obh
    u16* Wqkvt = xh    + (size_t)ROWS * HIDDEN;         // 3840x2560 (fused q|k|v weightsT)
    u16* Wot   = Wqkvt + (size_t)QKV_COLS * HIDDEN;     // 2560x2560
    u16* qkv   = Wot   + (size_t)QH_COLS * HIDDEN;      // 4096x3840 fused
    u16* obh   = xh;                                    // alias: x dead after projections

    dim3 blk(256);
    conv_bf16<<<(ROWS * HIDDEN / 4) / 256, blk, 0, stream>>>(x, xh);
    transpose_conv<<<dim3(QH_COLS / 64, HIDDEN / 64), blk, 0, stream>>>(Wq, Wqkvt, HIDDEN, QH_COLS);
    transpose_conv<<<dim3(KV_COLS / 64, HIDDEN / 64), blk, 0, stream>>>(Wk, Wqkvt + (size_t)QH_COLS * HIDDEN, HIDDEN, KV_COLS);
    transpose_conv<<<dim3(KV_COLS / 64, HIDDEN / 64), blk, 0, stream>>>(Wv, Wqkvt + (size_t)(QH_COLS + KV_COLS) * HIDDEN, HIDDEN, KV_COLS);
    transpose_conv<<<dim3(HIDDEN / 64, QH_COLS / 64), blk, 0, stream>>>(Wo, Wot, QH_COLS, HIDDEN);

    gemm256<u16><<<dim3(QKV_COLS / 256, ROWS / 256), dim3(512), 0, stream>>>(xh, Wqkvt, qkv, ROWS, QKV_COLS, HIDDEN);

    rope_bf16<<<(ROWS * (NH + NKV) * 40) / 256, blk, 0, stream>>>((__hip_bfloat16*)qkv, cf, sf);
    attn_mfma<<<dim3(16 * 64), blk, 0, stream>>>(qkv, obh);

    gemm256<float><<<dim3(HIDDEN / 256, ROWS / 256), dim3(512), 0, stream>>>(obh, Wot, out, ROWS, HIDDEN, QH_COLS);
}